// Round 9
// baseline (207.065 us; speedup 1.0000x reference)
//
#include <hip/hip_runtime.h>

// ---- problem constants: B=4, S=2048, D=1024, H=16, HD=64 ----
#define SEQ   2048
#define DM    1024
#define NHEAD 16
#define NBAT  4
#define NQKV  3072           // 3*DM
#define MTOT  8192           // NBAT*SEQ

typedef __attribute__((ext_vector_type(8))) short bf16x8;
typedef __attribute__((ext_vector_type(4))) float f32x4;
typedef __attribute__((ext_vector_type(8))) float f32x8;
typedef __attribute__((ext_vector_type(16))) float f32x16;
typedef __attribute__((ext_vector_type(2))) unsigned int uint2v;

__device__ __forceinline__ unsigned short f2bf(float f) {
    union { float f; unsigned int u; } v; v.f = f;
    return (unsigned short)((v.u + 0x7FFFu + ((v.u >> 16) & 1u)) >> 16);
}

// async global->LDS, 16B per lane. LDS dest must be wave-uniform base + lane*16.
__device__ __forceinline__ void gl_lds16(const void* g, void* l) {
    __builtin_amdgcn_global_load_lds(
        (const __attribute__((address_space(1))) unsigned int*)(unsigned long long)g,
        (__attribute__((address_space(3))) unsigned int*)(unsigned int)(unsigned long long)l,
        16, 0, 0);
}

// ---------------- fp32 -> bf16 convert (all three tensors, one launch) ----------------
__global__ __launch_bounds__(256) void k_cvt_all(const float* __restrict__ x,
                                                 const float* __restrict__ wq,
                                                 const float* __restrict__ wo,
                                                 unsigned short* __restrict__ xb,
                                                 unsigned short* __restrict__ wqb,
                                                 unsigned short* __restrict__ wob) {
    int i = blockIdx.x * 256 + threadIdx.x;          // float4 index, 0..3145727
    const float* s; unsigned short* d; int j;
    if (i < 2097152)      { s = x;  d = xb;  j = i; }
    else if (i < 2883584) { s = wq; d = wqb; j = i - 2097152; }
    else                  { s = wo; d = wob; j = i - 2883584; }
    float4 v = reinterpret_cast<const float4*>(s)[j];
    ushort4 o = { f2bf(v.x), f2bf(v.y), f2bf(v.z), f2bf(v.w) };
    reinterpret_cast<ushort4*>(d)[j] = o;
}

// ---------------- QKV GEMM: [8192,1024] x [3072,1024]^T -> scatter Q/K/Vt ----------------
// Counted-vmcnt 2-phase loop (T4): stage(kt+2) after read-complete barrier; never
// drain vmcnt to 0 in steady state (vmcnt(4) = next tile's 4 loads stay in flight).
__global__ __launch_bounds__(256) void k_qkv(const unsigned short* __restrict__ X,
                                             const unsigned short* __restrict__ W,
                                             const float* __restrict__ bias,
                                             unsigned short* __restrict__ Qb,
                                             unsigned short* __restrict__ Kb,
                                             unsigned short* __restrict__ Vtb) {
    __shared__ short As[2][128 * 32];
    __shared__ short Bs[2][128 * 32];

    const int tid = threadIdx.x;
    const int lane = tid & 63;
    const int wid = tid >> 6;
    const int lr = lane & 15, g = lane >> 4;
    // XCD-chunked swizzle (1536 wgs, 192/XCD)
    const int lb = (blockIdx.x & 7) * 192 + (blockIdx.x >> 3);
    const int bm = lb / (NQKV / 128);
    const int bn = lb % (NQKV / 128);
    const int m0 = bm * 128, n0 = bn * 128;
    const int wr = (wid >> 1) * 64, wc = (wid & 1) * 64;

    const f32x4 fz = {0.f, 0.f, 0.f, 0.f};
    f32x4 acc[4][4];
#pragma unroll
    for (int i = 0; i < 4; ++i)
#pragma unroll
        for (int j = 0; j < 4; ++j) acc[i][j] = fz;

    auto stage = [&](int buf, int kt) {   // 4 gl_lds per thread
#pragma unroll
        for (int p = 0; p < 2; ++p) {
            int c = wid * 128 + p * 64 + lane;     // 0..511
            int r_ = c >> 2;
            int kc = (c & 3) ^ (r_ & 3);           // inverse-swizzled global source
            gl_lds16(X + (size_t)(m0 + r_) * DM + kt * 32 + kc * 8, &As[buf][c * 8]);
            gl_lds16(W + (size_t)(n0 + r_) * DM + kt * 32 + kc * 8, &Bs[buf][c * 8]);
        }
    };

    stage(0, 0);
    stage(1, 1);

    for (int kt = 0; kt < 32; ++kt) {
        const int cur = kt & 1;
        if (kt < 31) asm volatile("s_waitcnt vmcnt(4)" ::: "memory");
        else         asm volatile("s_waitcnt vmcnt(0)" ::: "memory");
        __builtin_amdgcn_s_barrier();          // buf[cur] staged for everyone

        bf16x8 a[4], b[4];
#pragma unroll
        for (int i = 0; i < 4; ++i) {
            int ra = wr + i * 16 + lr;
            a[i] = *(const bf16x8*)&As[cur][ra * 32 + ((g ^ (ra & 3)) * 8)];
            int rb = wc + i * 16 + lr;
            b[i] = *(const bf16x8*)&Bs[cur][rb * 32 + ((g ^ (rb & 3)) * 8)];
        }
        asm volatile("s_waitcnt lgkmcnt(0)" ::: "memory");   // my reads complete
        __builtin_amdgcn_sched_barrier(0);                   // rule 18
        __builtin_amdgcn_s_barrier();          // all reads of buf[cur] complete
        if (kt + 2 < 32) stage(cur, kt + 2);   // safe to overwrite now

#pragma unroll
        for (int i = 0; i < 4; ++i)
#pragma unroll
            for (int j = 0; j < 4; ++j)
                acc[i][j] = __builtin_amdgcn_mfma_f32_16x16x32_bf16(a[i], b[j], acc[i][j], 0, 0, 0);
    }

    // epilogue: C/D layout col=lane&15, row=(lane>>4)*4+reg  [m89-verified]
#pragma unroll
    for (int j = 0; j < 4; ++j) {
        const int col = n0 + wc + j * 16 + lr;
        const int h = col / 192;
        const int cc = col - h * 192;
        const int part = cc >> 6;
        const int hd = cc & 63;
        const float bv = bias[col];
#pragma unroll
        for (int i = 0; i < 4; ++i) {
            const int mbase = m0 + wr + i * 16 + g * 4;
            const int b_ = mbase >> 11;
            const int s_ = mbase & 2047;
            const int bh = b_ * NHEAD + h;
            if (part == 2) {
                ushort4 pk = { f2bf(acc[i][j][0] + bv), f2bf(acc[i][j][1] + bv),
                               f2bf(acc[i][j][2] + bv), f2bf(acc[i][j][3] + bv) };
                *(ushort4*)&Vtb[((size_t)bh * 64 + hd) * SEQ + s_] = pk;
            } else {
#pragma unroll
                for (int r = 0; r < 4; ++r) {
                    const size_t idx = ((size_t)bh * SEQ + s_ + r) * 64 + hd;
                    float v = acc[i][j][r] + bv;
                    if (part == 0) Qb[idx] = f2bf(v * (0.125f * 1.44269504f));
                    else           Kb[idx] = f2bf(v);
                }
            }
        }
    }
}

// ---------------- flash attention (32x32 swapped-QK^T, QBLK=64/wave) ----------------
// grid = 64 heads * 8 q-tiles; block = 256 (4 waves, 64 q-rows each as 2 column blocks).
// K/V fragments read ONCE per wave-tile, reused for both q-blocks (halves LDS reads
// per FLOP). NO occupancy bound: R8's (256,2) capped VGPR at 128 and spilled ~12MB
// to scratch (WRITE_SIZE 16->24.7MB); uncapped needs ~220 VGPR -> 2 waves/SIMD clean.
__global__ __launch_bounds__(256) void k_attn(const unsigned short* __restrict__ Qb,
                                              const unsigned short* __restrict__ Kb,
                                              const unsigned short* __restrict__ Vtb,
                                              unsigned short* __restrict__ Ob) {
    __shared__ short Ks[2][64 * 64];   // [kpos 64][hd 64], 16B chunks XOR-swizzled by row&7
    __shared__ short Vs[2][64 * 64];   // [hd 64][k 64], same swizzle

    const int tid = threadIdx.x;
    const int lane = tid & 63;
    const int wid = tid >> 6;
    // XCD-chunked swizzle (512 wgs, 64/XCD): 8 whole heads per XCD -> K/V L2-resident
    const int lb = (blockIdx.x & 7) * 64 + (blockIdx.x >> 3);
    const int bh = lb >> 3;
    const int qt = lb & 7;
    const int c = lane & 31;
    const int hi = lane >> 5;

    const unsigned short* Qh = Qb + (size_t)bh * SEQ * 64;
    const unsigned short* Kh = Kb + (size_t)bh * SEQ * 64;
    const unsigned short* Vh = Vtb + (size_t)bh * 64 * SEQ;

    const int q0 = qt * 256 + wid * 64;

    // Q as B-operand, two column blocks: lane (c,hi) holds Q[q0+qb*32+c][kc*16+hi*8+j]
    bf16x8 qf[2][4];
#pragma unroll
    for (int qb = 0; qb < 2; ++qb)
#pragma unroll
        for (int kc = 0; kc < 4; ++kc)
            qf[qb][kc] = *(const bf16x8*)&Qh[(size_t)(q0 + qb * 32 + c) * 64 + kc * 16 + hi * 8];

    f32x16 oacc[2][2];    // [qb][nb]
    f32x8 lacc[2];        // per-qb row-sum partials (pair-compressed)
    f32x16 fz16;
#pragma unroll
    for (int r = 0; r < 16; ++r) {
        oacc[0][0][r] = 0.f; oacc[0][1][r] = 0.f;
        oacc[1][0][r] = 0.f; oacc[1][1][r] = 0.f;
        fz16[r] = 0.f;
    }
#pragma unroll
    for (int r = 0; r < 8; ++r) { lacc[0][r] = 0.f; lacc[1][r] = 0.f; }

    auto stageK = [&](int buf, int kt) {
#pragma unroll
        for (int p = 0; p < 2; ++p) {
            int ci = wid * 128 + p * 64 + lane;
            int r_ = ci >> 3;
            int kc = (ci & 7) ^ (r_ & 7);
            gl_lds16(Kh + (size_t)(kt * 64 + r_) * 64 + kc * 8, &Ks[buf][ci * 8]);
        }
    };
    auto stageV = [&](int buf, int kt) {
#pragma unroll
        for (int p = 0; p < 2; ++p) {
            int ci = wid * 128 + p * 64 + lane;
            int r_ = ci >> 3;
            int kc = (ci & 7) ^ (r_ & 7);
            gl_lds16(Vh + (size_t)r_ * SEQ + kt * 64 + kc * 8, &Vs[buf][ci * 8]);
        }
    };

    stageK(0, 0);
    stageV(0, 0);
    __syncthreads();

    // cur passed as a literal so LDS addresses are loop-invariant (hoisted once)
    auto tile = [&](int cur, int kt) {
        if (kt + 1 < 32) { stageK(cur ^ 1, kt + 1); stageV(cur ^ 1, kt + 1); }

        // K fragments once, reused for both q-blocks
        bf16x8 kf[2][4];
#pragma unroll
        for (int t = 0; t < 2; ++t) {
            const int row = t * 32 + c;
#pragma unroll
            for (int kc = 0; kc < 4; ++kc)
                kf[t][kc] = *(const bf16x8*)&Ks[cur][row * 64 + (((kc * 2 + hi) ^ (row & 7)) * 8)];
        }
        // V fragments once, reused for both q-blocks
        bf16x8 vf[2][4];
#pragma unroll
        for (int nb = 0; nb < 2; ++nb) {
            const int row = nb * 32 + c;
#pragma unroll
            for (int ks = 0; ks < 4; ++ks)
                vf[nb][ks] = *(const bf16x8*)&Vs[cur][row * 64 + (((ks * 2 + hi) ^ (row & 7)) * 8)];
        }

#pragma unroll
        for (int qb = 0; qb < 2; ++qb) {
            // St = K Q^T (swapped): D col=lane&31=q, row=kpos=(reg&3)+8*(reg>>2)+4*hi
            f32x16 st[2];
            __builtin_amdgcn_s_setprio(1);
#pragma unroll
            for (int t = 0; t < 2; ++t) {
                st[t] = __builtin_amdgcn_mfma_f32_32x32x16_bf16(kf[t][0], qf[qb][0], fz16, 0, 0, 0);
#pragma unroll
                for (int kc = 1; kc < 4; ++kc)
                    st[t] = __builtin_amdgcn_mfma_f32_32x32x16_bf16(kf[t][kc], qf[qb][kc], st[t], 0, 0, 0);
            }
            __builtin_amdgcn_s_setprio(0);

            // P = exp2(S); pair-compressed row-sum partials
#pragma unroll
            for (int t = 0; t < 2; ++t)
#pragma unroll
                for (int r = 0; r < 16; ++r)
                    st[t][r] = __builtin_amdgcn_exp2f(st[t][r]);
#pragma unroll
            for (int r = 0; r < 8; ++r)
                lacc[qb][r] += (st[0][2 * r] + st[0][2 * r + 1]) + (st[1][2 * r] + st[1][2 * r + 1]);

            // P -> bf16 A-fragments via cvt_pk + permlane32_swap (T12, R5-verified)
            bf16x8 pa[4];
#pragma unroll
            for (int t = 0; t < 2; ++t) {
                unsigned int qd[8];
#pragma unroll
                for (int i = 0; i < 8; ++i) {
                    float lo = st[t][2 * i], hg = st[t][2 * i + 1];
                    unsigned int d;
                    asm("v_cvt_pk_bf16_f32 %0, %1, %2" : "=v"(d) : "v"(lo), "v"(hg));
                    qd[i] = d;
                }
                uint2v s02 = __builtin_amdgcn_permlane32_swap(qd[0], qd[2], false, false);
                uint2v s13 = __builtin_amdgcn_permlane32_swap(qd[1], qd[3], false, false);
                uint2v s46 = __builtin_amdgcn_permlane32_swap(qd[4], qd[6], false, false);
                uint2v s57 = __builtin_amdgcn_permlane32_swap(qd[5], qd[7], false, false);
                union { unsigned int u[4]; bf16x8 v; } pk0, pk1;
                pk0.u[0] = s02.x; pk0.u[1] = s13.x; pk0.u[2] = s02.y; pk0.u[3] = s13.y;
                pk1.u[0] = s46.x; pk1.u[1] = s57.x; pk1.u[2] = s46.y; pk1.u[3] = s57.y;
                pa[t * 2] = pk0.v;
                pa[t * 2 + 1] = pk1.v;
            }

            // O += P V : D col=hd=nb*32+c, row=q over regs/hi
            __builtin_amdgcn_s_setprio(1);
#pragma unroll
            for (int ks = 0; ks < 4; ++ks) {
                oacc[qb][0] = __builtin_amdgcn_mfma_f32_32x32x16_bf16(pa[ks], vf[0][ks], oacc[qb][0], 0, 0, 0);
                oacc[qb][1] = __builtin_amdgcn_mfma_f32_32x32x16_bf16(pa[ks], vf[1][ks], oacc[qb][1], 0, 0, 0);
            }
            __builtin_amdgcn_s_setprio(0);
        }

        __syncthreads();
    };

    for (int kt = 0; kt < 32; kt += 2) { tile(0, kt); tile(1, kt + 1); }

    // epilogue per q-block: tree-sum partials, hi-half exchange, normalize, store
    const int b_ = bh >> 4, h_ = bh & 15;
#pragma unroll
    for (int qb = 0; qb < 2; ++qb) {
        float lred[8];
#pragma unroll
        for (int r = 0; r < 8; ++r) lred[r] = lacc[qb][r];
#pragma unroll
        for (int s2 = 4; s2 > 0; s2 >>= 1)
#pragma unroll
            for (int r = 0; r < s2; ++r) lred[r] += lred[r + s2];
        const float l_all = lred[0] + __shfl_xor(lred[0], 32);
        const float linv = 1.0f / l_all;
#pragma unroll
        for (int r = 0; r < 16; ++r) {
            const int qrow = (r & 3) + 8 * (r >> 2) + 4 * hi;
            const float fr = __shfl(linv, qrow);
            const size_t mrow = (size_t)b_ * SEQ + q0 + qb * 32 + qrow;
#pragma unroll
            for (int nb = 0; nb < 2; ++nb)
                Ob[mrow * DM + h_ * 64 + nb * 32 + c] = f2bf(oacc[qb][nb][r] * fr);
        }
    }
}

// ---------------- output GEMM: [8192,1024] x [1024,1024]^T + bias -> fp32 ----------------
// Same counted-vmcnt 2-phase loop as k_qkv.
__global__ __launch_bounds__(256) void k_out(const unsigned short* __restrict__ A,
                                             const unsigned short* __restrict__ W,
                                             const float* __restrict__ bias,
                                             float* __restrict__ O) {
    __shared__ short As[2][128 * 32];
    __shared__ short Bs[2][128 * 32];

    const int tid = threadIdx.x;
    const int lane = tid & 63;
    const int wid = tid >> 6;
    const int lr = lane & 15, g = lane >> 4;
    // XCD-chunked swizzle (512 wgs, 64/XCD)
    const int lb = (blockIdx.x & 7) * 64 + (blockIdx.x >> 3);
    const int bm = lb / (DM / 128);
    const int bn = lb % (DM / 128);
    const int m0 = bm * 128, n0 = bn * 128;
    const int wr = (wid >> 1) * 64, wc = (wid & 1) * 64;

    const f32x4 fz = {0.f, 0.f, 0.f, 0.f};
    f32x4 acc[4][4];
#pragma unroll
    for (int i = 0; i < 4; ++i)
#pragma unroll
        for (int j = 0; j < 4; ++j) acc[i][j] = fz;

    auto stage = [&](int buf, int kt) {
#pragma unroll
        for (int p = 0; p < 2; ++p) {
            int c = wid * 128 + p * 64 + lane;
            int r_ = c >> 2;
            int kc = (c & 3) ^ (r_ & 3);
            gl_lds16(A + (size_t)(m0 + r_) * DM + kt * 32 + kc * 8, &As[buf][c * 8]);
            gl_lds16(W + (size_t)(n0 + r_) * DM + kt * 32 + kc * 8, &Bs[buf][c * 8]);
        }
    };

    stage(0, 0);
    stage(1, 1);

    for (int kt = 0; kt < 32; ++kt) {
        const int cur = kt & 1;
        if (kt < 31) asm volatile("s_waitcnt vmcnt(4)" ::: "memory");
        else         asm volatile("s_waitcnt vmcnt(0)" ::: "memory");
        __builtin_amdgcn_s_barrier();

        bf16x8 a[4], b[4];
#pragma unroll
        for (int i = 0; i < 4; ++i) {
            int ra = wr + i * 16 + lr;
            a[i] = *(const bf16x8*)&As[cur][ra * 32 + ((g ^ (ra & 3)) * 8)];
            int rb = wc + i * 16 + lr;
            b[i] = *(const bf16x8*)&Bs[cur][rb * 32 + ((g ^ (rb & 3)) * 8)];
        }
        asm volatile("s_waitcnt lgkmcnt(0)" ::: "memory");
        __builtin_amdgcn_sched_barrier(0);
        __builtin_amdgcn_s_barrier();
        if (kt + 2 < 32) stage(cur, kt + 2);

#pragma unroll
        for (int i = 0; i < 4; ++i)
#pragma unroll
            for (int j = 0; j < 4; ++j)
                acc[i][j] = __builtin_amdgcn_mfma_f32_16x16x32_bf16(a[i], b[j], acc[i][j], 0, 0, 0);
    }

#pragma unroll
    for (int j = 0; j < 4; ++j) {
        const int col = n0 + wc + j * 16 + lr;
        const float bv = bias[col];
#pragma unroll
        for (int i = 0; i < 4; ++i) {
            const int mb = m0 + wr + i * 16 + g * 4;
#pragma unroll
            for (int r = 0; r < 4; ++r)
                O[(size_t)(mb + r) * DM + col] = acc[i][j][r] + bv;
        }
    }
}

extern "C" void kernel_launch(void* const* d_in, const int* in_sizes, int n_in,
                              void* d_out, int out_size, void* d_ws, size_t ws_size,
                              hipStream_t stream) {
    const float* x    = (const float*)d_in[0];
    const float* Wqkv = (const float*)d_in[1];
    const float* bqkv = (const float*)d_in[2];
    const float* Wout = (const float*)d_in[3];
    const float* bout = (const float*)d_in[4];
    float* out = (float*)d_out;

    char* ws = (char*)d_ws;                                     // needs 88 MB
    unsigned short* xb   = (unsigned short*)(ws);               // 16 MB  x bf16
    unsigned short* wqb  = (unsigned short*)(ws + (16u << 20)); // 6 MB W_qkv bf16
    unsigned short* wob  = (unsigned short*)(ws + (22u << 20)); // 2 MB W_out bf16
    unsigned short* Qb   = (unsigned short*)(ws + (24u << 20)); // 16 MB
    unsigned short* Kb   = (unsigned short*)(ws + (40u << 20)); // 16 MB
    unsigned short* Vtb  = (unsigned short*)(ws + (56u << 20)); // 16 MB
    unsigned short* valb = (unsigned short*)(ws + (72u << 20)); // 16 MB

    k_cvt_all<<<12288, 256, 0, stream>>>(x, Wqkv, Wout, xb, wqb, wob);
    k_qkv<<<64 * 24, 256, 0, stream>>>(xb, wqb, bqkv, Qb, Kb, Vtb);
    k_attn<<<64 * 8, 256, 0, stream>>>(Qb, Kb, Vtb, valb);
    k_out<<<64 * 8, 256, 0, stream>>>(valb, wob, bout, out);
}

// Round 10
// 200.992 us; speedup vs baseline: 1.0302x; 1.0302x over previous
//
#include <hip/hip_runtime.h>

// ---- problem constants: B=4, S=2048, D=1024, H=16, HD=64 ----
#define SEQ   2048
#define DM    1024
#define NHEAD 16
#define NBAT  4
#define NQKV  3072           // 3*DM
#define MTOT  8192           // NBAT*SEQ

typedef __attribute__((ext_vector_type(8))) short bf16x8;
typedef __attribute__((ext_vector_type(4))) float f32x4;
typedef __attribute__((ext_vector_type(16))) float f32x16;
typedef __attribute__((ext_vector_type(2))) unsigned int uint2v;

__device__ __forceinline__ unsigned short f2bf(float f) {
    union { float f; unsigned int u; } v; v.f = f;
    return (unsigned short)((v.u + 0x7FFFu + ((v.u >> 16) & 1u)) >> 16);
}

// async global->LDS, 16B per lane. LDS dest must be wave-uniform base + lane*16.
__device__ __forceinline__ void gl_lds16(const void* g, void* l) {
    __builtin_amdgcn_global_load_lds(
        (const __attribute__((address_space(1))) unsigned int*)(unsigned long long)g,
        (__attribute__((address_space(3))) unsigned int*)(unsigned int)(unsigned long long)l,
        16, 0, 0);
}

// ---------------- fp32 -> bf16 convert (weights only; x fused into k_qkv) ----------------
__global__ __launch_bounds__(256) void k_cvt_w(const float* __restrict__ wq,
                                               const float* __restrict__ wo,
                                               unsigned short* __restrict__ wqb,
                                               unsigned short* __restrict__ wob) {
    int i = blockIdx.x * 256 + threadIdx.x;          // float4 index, 0..1048575
    const float* s; unsigned short* d; int j;
    if (i < 786432) { s = wq; d = wqb; j = i; }
    else            { s = wo; d = wob; j = i - 786432; }
    float4 v = reinterpret_cast<const float4*>(s)[j];
    ushort4 o = { f2bf(v.x), f2bf(v.y), f2bf(v.z), f2bf(v.w) };
    reinterpret_cast<ushort4*>(d)[j] = o;
}

// ---------------- QKV GEMM: fp32 x [8192,1024] · bf16 W[3072,1024]^T -> Q/K/Vt ----------------
// A staged as fp32 [128][32] (16KB/buf), converted to bf16 fragments after ds_read
// (v_cvt_pk_bf16_f32). Counted-vmcnt loop: 6 loads/stage -> steady-state vmcnt(6).
__global__ __launch_bounds__(256) void k_qkv(const float* __restrict__ X,
                                             const unsigned short* __restrict__ W,
                                             const float* __restrict__ bias,
                                             unsigned short* __restrict__ Qb,
                                             unsigned short* __restrict__ Kb,
                                             unsigned short* __restrict__ Vtb) {
    __shared__ float Asf[2][128 * 32];   // fp32 A tile, 8 chunks/row, XOR (r&7)
    __shared__ short Bs[2][128 * 32];    // bf16 B tile, 4 chunks/row, XOR (r&3)

    const int tid = threadIdx.x;
    const int lane = tid & 63;
    const int wid = tid >> 6;
    const int lr = lane & 15, g = lane >> 4;
    // XCD-chunked swizzle (1536 wgs, 192/XCD)
    const int lb = (blockIdx.x & 7) * 192 + (blockIdx.x >> 3);
    const int bm = lb / (NQKV / 128);
    const int bn = lb % (NQKV / 128);
    const int m0 = bm * 128, n0 = bn * 128;
    const int wr = (wid >> 1) * 64, wc = (wid & 1) * 64;

    const f32x4 fz = {0.f, 0.f, 0.f, 0.f};
    f32x4 acc[4][4];
#pragma unroll
    for (int i = 0; i < 4; ++i)
#pragma unroll
        for (int j = 0; j < 4; ++j) acc[i][j] = fz;

    auto stage = [&](int buf, int kt) {   // 6 gl_lds per thread (4 A-f32 + 2 B-bf16)
#pragma unroll
        for (int p = 0; p < 4; ++p) {
            int c = p * 256 + tid;         // 0..1023 chunks of 16B (= 4 floats)
            int r_ = c >> 3;
            int kc = (c & 7) ^ (r_ & 7);   // inverse-swizzled global source
            gl_lds16(X + (size_t)(m0 + r_) * DM + kt * 32 + kc * 4, &Asf[buf][c * 4]);
        }
#pragma unroll
        for (int p = 0; p < 2; ++p) {
            int c = p * 256 + tid;         // 0..511 chunks of 16B (= 8 bf16)
            int r_ = c >> 2;
            int kc = (c & 3) ^ (r_ & 3);
            gl_lds16(W + (size_t)(n0 + r_) * DM + kt * 32 + kc * 8, &Bs[buf][c * 8]);
        }
    };

    stage(0, 0);
    stage(1, 1);

    for (int kt = 0; kt < 32; ++kt) {
        const int cur = kt & 1;
        if (kt < 31) asm volatile("s_waitcnt vmcnt(6)" ::: "memory");
        else         asm volatile("s_waitcnt vmcnt(0)" ::: "memory");
        __builtin_amdgcn_s_barrier();          // buf[cur] staged for everyone

        // A: two f32 16B-chunks per fragment (k-elems g*8..g*8+7), B: one bf16 chunk
        float4 alo[4], ahi[4];
        bf16x8 b[4];
#pragma unroll
        for (int i = 0; i < 4; ++i) {
            int ra = wr + i * 16 + lr;
            const float* Ar = &Asf[cur][ra * 32];
            alo[i] = *(const float4*)&Ar[(((2 * g) ^ (ra & 7)) * 4)];
            ahi[i] = *(const float4*)&Ar[(((2 * g + 1) ^ (ra & 7)) * 4)];
            int rb = wc + i * 16 + lr;
            b[i] = *(const bf16x8*)&Bs[cur][rb * 32 + ((g ^ (rb & 3)) * 8)];
        }
        asm volatile("s_waitcnt lgkmcnt(0)" ::: "memory");   // my reads complete
        __builtin_amdgcn_sched_barrier(0);                   // rule 18
        __builtin_amdgcn_s_barrier();          // all reads of buf[cur] complete
        if (kt + 2 < 32) stage(cur, kt + 2);   // safe to overwrite now

        bf16x8 a[4];
#pragma unroll
        for (int i = 0; i < 4; ++i) {
            union { unsigned int u[4]; bf16x8 v; } av;
            asm("v_cvt_pk_bf16_f32 %0, %1, %2" : "=v"(av.u[0]) : "v"(alo[i].x), "v"(alo[i].y));
            asm("v_cvt_pk_bf16_f32 %0, %1, %2" : "=v"(av.u[1]) : "v"(alo[i].z), "v"(alo[i].w));
            asm("v_cvt_pk_bf16_f32 %0, %1, %2" : "=v"(av.u[2]) : "v"(ahi[i].x), "v"(ahi[i].y));
            asm("v_cvt_pk_bf16_f32 %0, %1, %2" : "=v"(av.u[3]) : "v"(ahi[i].z), "v"(ahi[i].w));
            a[i] = av.v;
        }

#pragma unroll
        for (int i = 0; i < 4; ++i)
#pragma unroll
            for (int j = 0; j < 4; ++j)
                acc[i][j] = __builtin_amdgcn_mfma_f32_16x16x32_bf16(a[i], b[j], acc[i][j], 0, 0, 0);
    }

    // epilogue: C/D layout col=lane&15, row=(lane>>4)*4+reg  [m89-verified]
#pragma unroll
    for (int j = 0; j < 4; ++j) {
        const int col = n0 + wc + j * 16 + lr;
        const int h = col / 192;
        const int cc = col - h * 192;
        const int part = cc >> 6;
        const int hd = cc & 63;
        const float bv = bias[col];
#pragma unroll
        for (int i = 0; i < 4; ++i) {
            const int mbase = m0 + wr + i * 16 + g * 4;
            const int b_ = mbase >> 11;
            const int s_ = mbase & 2047;
            const int bh = b_ * NHEAD + h;
            if (part == 2) {
                ushort4 pk = { f2bf(acc[i][j][0] + bv), f2bf(acc[i][j][1] + bv),
                               f2bf(acc[i][j][2] + bv), f2bf(acc[i][j][3] + bv) };
                *(ushort4*)&Vtb[((size_t)bh * 64 + hd) * SEQ + s_] = pk;
            } else {
#pragma unroll
                for (int r = 0; r < 4; ++r) {
                    const size_t idx = ((size_t)bh * SEQ + s_ + r) * 64 + hd;
                    float v = acc[i][j][r] + bv;
                    if (part == 0) Qb[idx] = f2bf(v * (0.125f * 1.44269504f));
                    else           Kb[idx] = f2bf(v);
                }
            }
        }
    }
}

// ---------------- flash attention (32x32 swapped-QK^T, QBLK=32/wave — R7-proven) ----------------
// grid = 64 heads * 16 q-tiles; block = 256 (4 waves, 32 q-rows each).
// R8/R9 showed QBLK=64 loses either to spills (VGPR cap) or occupancy (uncapped);
// this 124-VGPR point is the structure's optimum.
__global__ __launch_bounds__(256) void k_attn(const unsigned short* __restrict__ Qb,
                                              const unsigned short* __restrict__ Kb,
                                              const unsigned short* __restrict__ Vtb,
                                              unsigned short* __restrict__ Ob) {
    __shared__ short Ks[2][64 * 64];   // [kpos 64][hd 64], 16B chunks XOR-swizzled by row&7
    __shared__ short Vs[2][64 * 64];   // [hd 64][k 64], same swizzle

    const int tid = threadIdx.x;
    const int lane = tid & 63;
    const int wid = tid >> 6;
    // XCD-chunked swizzle (1024 wgs, 128/XCD): 8 whole heads per XCD -> K/V L2-resident
    const int lb = (blockIdx.x & 7) * 128 + (blockIdx.x >> 3);
    const int bh = lb >> 4;
    const int qt = lb & 15;
    const int c = lane & 31;
    const int hi = lane >> 5;

    const unsigned short* Qh = Qb + (size_t)bh * SEQ * 64;
    const unsigned short* Kh = Kb + (size_t)bh * SEQ * 64;
    const unsigned short* Vh = Vtb + (size_t)bh * 64 * SEQ;

    const int q0 = qt * 128 + wid * 32;

    // Q as B-operand: lane (c,hi) holds Q[q0+c][kc*16 + hi*8 + j]
    bf16x8 qf[4];
#pragma unroll
    for (int kc = 0; kc < 4; ++kc)
        qf[kc] = *(const bf16x8*)&Qh[(size_t)(q0 + c) * 64 + kc * 16 + hi * 8];

    f32x16 oacc[2];
    f32x16 lacc;
    f32x16 fz16;
#pragma unroll
    for (int r = 0; r < 16; ++r) { oacc[0][r] = 0.f; oacc[1][r] = 0.f; lacc[r] = 0.f; fz16[r] = 0.f; }

    auto stageK = [&](int buf, int kt) {
#pragma unroll
        for (int p = 0; p < 2; ++p) {
            int ci = wid * 128 + p * 64 + lane;
            int r_ = ci >> 3;
            int kc = (ci & 7) ^ (r_ & 7);
            gl_lds16(Kh + (size_t)(kt * 64 + r_) * 64 + kc * 8, &Ks[buf][ci * 8]);
        }
    };
    auto stageV = [&](int buf, int kt) {
#pragma unroll
        for (int p = 0; p < 2; ++p) {
            int ci = wid * 128 + p * 64 + lane;
            int r_ = ci >> 3;
            int kc = (ci & 7) ^ (r_ & 7);
            gl_lds16(Vh + (size_t)r_ * SEQ + kt * 64 + kc * 8, &Vs[buf][ci * 8]);
        }
    };

    stageK(0, 0);
    stageV(0, 0);
    __syncthreads();

    // cur passed as a literal so LDS addresses are loop-invariant (hoisted once)
    auto tile = [&](int cur, int kt) {
        if (kt + 1 < 32) { stageK(cur ^ 1, kt + 1); stageV(cur ^ 1, kt + 1); }

        // St = K Q^T  (swapped): D col=lane&31=q, row=kpos=(reg&3)+8*(reg>>2)+4*hi
        f32x16 st[2];
        __builtin_amdgcn_s_setprio(1);
#pragma unroll
        for (int t = 0; t < 2; ++t) {
            const int row = t * 32 + c;
            bf16x8 kf0 = *(const bf16x8*)&Ks[cur][row * 64 + (((hi) ^ (row & 7)) * 8)];
            st[t] = __builtin_amdgcn_mfma_f32_32x32x16_bf16(kf0, qf[0], fz16, 0, 0, 0);
#pragma unroll
            for (int kc = 1; kc < 4; ++kc) {
                bf16x8 kf = *(const bf16x8*)&Ks[cur][row * 64 + (((kc * 2 + hi) ^ (row & 7)) * 8)];
                st[t] = __builtin_amdgcn_mfma_f32_32x32x16_bf16(kf, qf[kc], st[t], 0, 0, 0);
            }
        }
        __builtin_amdgcn_s_setprio(0);

        // V fragments issued EARLY: their ds_read latency hides under softmax VALU
        bf16x8 vf[2][4];
#pragma unroll
        for (int nb = 0; nb < 2; ++nb) {
            const int row = nb * 32 + c;
#pragma unroll
            for (int ks = 0; ks < 4; ++ks)
                vf[nb][ks] = *(const bf16x8*)&Vs[cur][row * 64 + (((ks * 2 + hi) ^ (row & 7)) * 8)];
        }

        // P = exp2(S); accumulate row-sum partials per-reg (tree deferred to epilogue)
#pragma unroll
        for (int t = 0; t < 2; ++t)
#pragma unroll
            for (int r = 0; r < 16; ++r)
                st[t][r] = __builtin_amdgcn_exp2f(st[t][r]);
#pragma unroll
        for (int r = 0; r < 16; ++r)
            lacc[r] += st[0][r] + st[1][r];

        // P -> bf16 A-fragments via cvt_pk + permlane32_swap (T12, R5-verified)
        bf16x8 pa[4];
#pragma unroll
        for (int t = 0; t < 2; ++t) {
            unsigned int qd[8];
#pragma unroll
            for (int i = 0; i < 8; ++i) {
                float lo = st[t][2 * i], hg = st[t][2 * i + 1];
                unsigned int d;
                asm("v_cvt_pk_bf16_f32 %0, %1, %2" : "=v"(d) : "v"(lo), "v"(hg));
                qd[i] = d;
            }
            uint2v s02 = __builtin_amdgcn_permlane32_swap(qd[0], qd[2], false, false);
            uint2v s13 = __builtin_amdgcn_permlane32_swap(qd[1], qd[3], false, false);
            uint2v s46 = __builtin_amdgcn_permlane32_swap(qd[4], qd[6], false, false);
            uint2v s57 = __builtin_amdgcn_permlane32_swap(qd[5], qd[7], false, false);
            union { unsigned int u[4]; bf16x8 v; } pk0, pk1;
            pk0.u[0] = s02.x; pk0.u[1] = s13.x; pk0.u[2] = s02.y; pk0.u[3] = s13.y;
            pk1.u[0] = s46.x; pk1.u[1] = s57.x; pk1.u[2] = s46.y; pk1.u[3] = s57.y;
            pa[t * 2] = pk0.v;
            pa[t * 2 + 1] = pk1.v;
        }

        // O += P V : A=pa (row=q), B=V[k][hd]; D col=hd=nb*32+c, row=q over regs/hi
        __builtin_amdgcn_s_setprio(1);
#pragma unroll
        for (int ks = 0; ks < 4; ++ks) {
            oacc[0] = __builtin_amdgcn_mfma_f32_32x32x16_bf16(pa[ks], vf[0][ks], oacc[0], 0, 0, 0);
            oacc[1] = __builtin_amdgcn_mfma_f32_32x32x16_bf16(pa[ks], vf[1][ks], oacc[1], 0, 0, 0);
        }
        __builtin_amdgcn_s_setprio(0);

        __syncthreads();
    };

    for (int kt = 0; kt < 32; kt += 2) { tile(0, kt); tile(1, kt + 1); }

    // final row-sum: tree over the 16 partials, then hi-half exchange
    float lred[16];
#pragma unroll
    for (int r = 0; r < 16; ++r) lred[r] = lacc[r];
#pragma unroll
    for (int s2 = 8; s2 > 0; s2 >>= 1)
#pragma unroll
        for (int r = 0; r < s2; ++r) lred[r] += lred[r + s2];
    const float l_all = lred[0] + __shfl_xor(lred[0], 32);

    // epilogue: O[q][hd] with q=(r&3)+8*(r>>2)+4*hi, hd=nb*32+c; l gathered per row
    const int b_ = bh >> 4, h_ = bh & 15;
    const float linv = 1.0f / l_all;
#pragma unroll
    for (int r = 0; r < 16; ++r) {
        const int qrow = (r & 3) + 8 * (r >> 2) + 4 * hi;
        const float fr = __shfl(linv, qrow);
        const size_t mrow = (size_t)b_ * SEQ + q0 + qrow;
#pragma unroll
        for (int nb = 0; nb < 2; ++nb)
            Ob[mrow * DM + h_ * 64 + nb * 32 + c] = f2bf(oacc[nb][r] * fr);
    }
}

// ---------------- output GEMM: [8192,1024] x [1024,1024]^T + bias -> fp32 ----------------
// Counted-vmcnt 2-phase loop (4 loads/stage -> vmcnt(4)).
__global__ __launch_bounds__(256) void k_out(const unsigned short* __restrict__ A,
                                             const unsigned short* __restrict__ W,
                                             const float* __restrict__ bias,
                                             float* __restrict__ O) {
    __shared__ short As[2][128 * 32];
    __shared__ short Bs[2][128 * 32];

    const int tid = threadIdx.x;
    const int lane = tid & 63;
    const int wid = tid >> 6;
    const int lr = lane & 15, g = lane >> 4;
    // XCD-chunked swizzle (512 wgs, 64/XCD)
    const int lb = (blockIdx.x & 7) * 64 + (blockIdx.x >> 3);
    const int bm = lb / (DM / 128);
    const int bn = lb % (DM / 128);
    const int m0 = bm * 128, n0 = bn * 128;
    const int wr = (wid >> 1) * 64, wc = (wid & 1) * 64;

    const f32x4 fz = {0.f, 0.f, 0.f, 0.f};
    f32x4 acc[4][4];
#pragma unroll
    for (int i = 0; i < 4; ++i)
#pragma unroll
        for (int j = 0; j < 4; ++j) acc[i][j] = fz;

    auto stage = [&](int buf, int kt) {
#pragma unroll
        for (int p = 0; p < 2; ++p) {
            int c = wid * 128 + p * 64 + lane;
            int r_ = c >> 2;
            int kc = (c & 3) ^ (r_ & 3);
            gl_lds16(A + (size_t)(m0 + r_) * DM + kt * 32 + kc * 8, &As[buf][c * 8]);
            gl_lds16(W + (size_t)(n0 + r_) * DM + kt * 32 + kc * 8, &Bs[buf][c * 8]);
        }
    };

    stage(0, 0);
    stage(1, 1);

    for (int kt = 0; kt < 32; ++kt) {
        const int cur = kt & 1;
        if (kt < 31) asm volatile("s_waitcnt vmcnt(4)" ::: "memory");
        else         asm volatile("s_waitcnt vmcnt(0)" ::: "memory");
        __builtin_amdgcn_s_barrier();

        bf16x8 a[4], b[4];
#pragma unroll
        for (int i = 0; i < 4; ++i) {
            int ra = wr + i * 16 + lr;
            a[i] = *(const bf16x8*)&As[cur][ra * 32 + ((g ^ (ra & 3)) * 8)];
            int rb = wc + i * 16 + lr;
            b[i] = *(const bf16x8*)&Bs[cur][rb * 32 + ((g ^ (rb & 3)) * 8)];
        }
        asm volatile("s_waitcnt lgkmcnt(0)" ::: "memory");
        __builtin_amdgcn_sched_barrier(0);
        __builtin_amdgcn_s_barrier();
        if (kt + 2 < 32) stage(cur, kt + 2);

#pragma unroll
        for (int i = 0; i < 4; ++i)
#pragma unroll
            for (int j = 0; j < 4; ++j)
                acc[i][j] = __builtin_amdgcn_mfma_f32_16x16x32_bf16(a[i], b[j], acc[i][j], 0, 0, 0);
    }

#pragma unroll
    for (int j = 0; j < 4; ++j) {
        const int col = n0 + wc + j * 16 + lr;
        const float bv = bias[col];
#pragma unroll
        for (int i = 0; i < 4; ++i) {
            const int mb = m0 + wr + i * 16 + g * 4;
#pragma unroll
            for (int r = 0; r < 4; ++r)
                O[(size_t)(mb + r) * DM + col] = acc[i][j][r] + bv;
        }
    }
}

extern "C" void kernel_launch(void* const* d_in, const int* in_sizes, int n_in,
                              void* d_out, int out_size, void* d_ws, size_t ws_size,
                              hipStream_t stream) {
    const float* x    = (const float*)d_in[0];
    const float* Wqkv = (const float*)d_in[1];
    const float* bqkv = (const float*)d_in[2];
    const float* Wout = (const float*)d_in[3];
    const float* bout = (const float*)d_in[4];
    float* out = (float*)d_out;

    char* ws = (char*)d_ws;                                     // needs 88 MB
    unsigned short* wqb  = (unsigned short*)(ws + (16u << 20)); // 6 MB W_qkv bf16
    unsigned short* wob  = (unsigned short*)(ws + (22u << 20)); // 2 MB W_out bf16
    unsigned short* Qb   = (unsigned short*)(ws + (24u << 20)); // 16 MB
    unsigned short* Kb   = (unsigned short*)(ws + (40u << 20)); // 16 MB
    unsigned short* Vtb  = (unsigned short*)(ws + (56u << 20)); // 16 MB
    unsigned short* valb = (unsigned short*)(ws + (72u << 20)); // 16 MB

    k_cvt_w<<<4096, 256, 0, stream>>>(Wqkv, Wout, wqb, wob);
    k_qkv<<<64 * 24, 256, 0, stream>>>(x, wqb, bqkv, Qb, Kb, Vtb);
    k_attn<<<64 * 16, 256, 0, stream>>>(Qb, Kb, Vtb, valb);
    k_out<<<64 * 8, 256, 0, stream>>>(valb, wob, bout, out);
}

// Round 11
// 194.137 us; speedup vs baseline: 1.0666x; 1.0353x over previous
//
#include <hip/hip_runtime.h>

// ---- problem constants: B=4, S=2048, D=1024, H=16, HD=64 ----
#define SEQ   2048
#define DM    1024
#define NHEAD 16
#define NBAT  4
#define NQKV  3072           // 3*DM
#define MTOT  8192           // NBAT*SEQ

typedef __attribute__((ext_vector_type(8))) short bf16x8;
typedef __attribute__((ext_vector_type(4))) float f32x4;
typedef __attribute__((ext_vector_type(16))) float f32x16;
typedef __attribute__((ext_vector_type(2))) unsigned int uint2v;

__device__ __forceinline__ unsigned short f2bf(float f) {
    union { float f; unsigned int u; } v; v.f = f;
    return (unsigned short)((v.u + 0x7FFFu + ((v.u >> 16) & 1u)) >> 16);
}

// async global->LDS, 16B per lane. LDS dest must be wave-uniform base + lane*16.
__device__ __forceinline__ void gl_lds16(const void* g, void* l) {
    __builtin_amdgcn_global_load_lds(
        (const __attribute__((address_space(1))) unsigned int*)(unsigned long long)g,
        (__attribute__((address_space(3))) unsigned int*)(unsigned int)(unsigned long long)l,
        16, 0, 0);
}

// ---------------- fp32 -> bf16 convert (all three tensors, one launch) ----------------
// boundaries are multiples of 64 -> wave-uniform source selection
__global__ __launch_bounds__(256) void k_cvt_all(const float* __restrict__ x,
                                                 const float* __restrict__ wq,
                                                 const float* __restrict__ wo,
                                                 unsigned short* __restrict__ xb,
                                                 unsigned short* __restrict__ wqb,
                                                 unsigned short* __restrict__ wob) {
    int i = blockIdx.x * 256 + threadIdx.x;          // float4 index, 0..3145727
    const float* s; unsigned short* d; int j;
    if (i < 2097152)      { s = x;  d = xb;  j = i; }
    else if (i < 2883584) { s = wq; d = wqb; j = i - 2097152; }
    else                  { s = wo; d = wob; j = i - 2883584; }
    float4 v = reinterpret_cast<const float4*>(s)[j];
    ushort4 o = { f2bf(v.x), f2bf(v.y), f2bf(v.z), f2bf(v.w) };
    reinterpret_cast<ushort4*>(d)[j] = o;
}

// ---------------- QKV GEMM: [8192,1024] x [3072,1024]^T -> scatter Q/K/Vt ----------------
// Counted-vmcnt 2-phase loop (T4): stage(kt+2) after read-complete barrier; never
// drain vmcnt to 0 in steady state (vmcnt(4) = next tile's 4 loads stay in flight).
// bf16 A staging (R10: fp32-A staging doubles staged bytes + blows per-XCD L2 ->
// FETCH 159MB, k_qkv 50->107us. Convert once in k_cvt_all instead.)
__global__ __launch_bounds__(256) void k_qkv(const unsigned short* __restrict__ X,
                                             const unsigned short* __restrict__ W,
                                             const float* __restrict__ bias,
                                             unsigned short* __restrict__ Qb,
                                             unsigned short* __restrict__ Kb,
                                             unsigned short* __restrict__ Vtb) {
    __shared__ short As[2][128 * 32];
    __shared__ short Bs[2][128 * 32];

    const int tid = threadIdx.x;
    const int lane = tid & 63;
    const int wid = tid >> 6;
    const int lr = lane & 15, g = lane >> 4;
    // XCD-chunked swizzle (1536 wgs, 192/XCD)
    const int lb = (blockIdx.x & 7) * 192 + (blockIdx.x >> 3);
    const int bm = lb / (NQKV / 128);
    const int bn = lb % (NQKV / 128);
    const int m0 = bm * 128, n0 = bn * 128;
    const int wr = (wid >> 1) * 64, wc = (wid & 1) * 64;

    const f32x4 fz = {0.f, 0.f, 0.f, 0.f};
    f32x4 acc[4][4];
#pragma unroll
    for (int i = 0; i < 4; ++i)
#pragma unroll
        for (int j = 0; j < 4; ++j) acc[i][j] = fz;

    auto stage = [&](int buf, int kt) {   // 4 gl_lds per thread
#pragma unroll
        for (int p = 0; p < 2; ++p) {
            int c = wid * 128 + p * 64 + lane;     // 0..511
            int r_ = c >> 2;
            int kc = (c & 3) ^ (r_ & 3);           // inverse-swizzled global source
            gl_lds16(X + (size_t)(m0 + r_) * DM + kt * 32 + kc * 8, &As[buf][c * 8]);
            gl_lds16(W + (size_t)(n0 + r_) * DM + kt * 32 + kc * 8, &Bs[buf][c * 8]);
        }
    };

    stage(0, 0);
    stage(1, 1);

    for (int kt = 0; kt < 32; ++kt) {
        const int cur = kt & 1;
        if (kt < 31) asm volatile("s_waitcnt vmcnt(4)" ::: "memory");
        else         asm volatile("s_waitcnt vmcnt(0)" ::: "memory");
        __builtin_amdgcn_s_barrier();          // buf[cur] staged for everyone

        bf16x8 a[4], b[4];
#pragma unroll
        for (int i = 0; i < 4; ++i) {
            int ra = wr + i * 16 + lr;
            a[i] = *(const bf16x8*)&As[cur][ra * 32 + ((g ^ (ra & 3)) * 8)];
            int rb = wc + i * 16 + lr;
            b[i] = *(const bf16x8*)&Bs[cur][rb * 32 + ((g ^ (rb & 3)) * 8)];
        }
        asm volatile("s_waitcnt lgkmcnt(0)" ::: "memory");   // my reads complete
        __builtin_amdgcn_sched_barrier(0);                   // rule 18
        __builtin_amdgcn_s_barrier();          // all reads of buf[cur] complete
        if (kt + 2 < 32) stage(cur, kt + 2);   // safe to overwrite now

#pragma unroll
        for (int i = 0; i < 4; ++i)
#pragma unroll
            for (int j = 0; j < 4; ++j)
                acc[i][j] = __builtin_amdgcn_mfma_f32_16x16x32_bf16(a[i], b[j], acc[i][j], 0, 0, 0);
    }

    // epilogue: C/D layout col=lane&15, row=(lane>>4)*4+reg  [m89-verified]
#pragma unroll
    for (int j = 0; j < 4; ++j) {
        const int col = n0 + wc + j * 16 + lr;
        const int h = col / 192;
        const int cc = col - h * 192;
        const int part = cc >> 6;
        const int hd = cc & 63;
        const float bv = bias[col];
#pragma unroll
        for (int i = 0; i < 4; ++i) {
            const int mbase = m0 + wr + i * 16 + g * 4;
            const int b_ = mbase >> 11;
            const int s_ = mbase & 2047;
            const int bh = b_ * NHEAD + h;
            if (part == 2) {
                ushort4 pk = { f2bf(acc[i][j][0] + bv), f2bf(acc[i][j][1] + bv),
                               f2bf(acc[i][j][2] + bv), f2bf(acc[i][j][3] + bv) };
                *(ushort4*)&Vtb[((size_t)bh * 64 + hd) * SEQ + s_] = pk;
            } else {
#pragma unroll
                for (int r = 0; r < 4; ++r) {
                    const size_t idx = ((size_t)bh * SEQ + s_ + r) * 64 + hd;
                    float v = acc[i][j][r] + bv;
                    if (part == 0) Qb[idx] = f2bf(v * (0.125f * 1.44269504f));
                    else           Kb[idx] = f2bf(v);
                }
            }
        }
    }
}

// ---------------- flash attention (32x32 swapped-QK^T, QBLK=32/wave — R7-proven) ----------------
// grid = 64 heads * 16 q-tiles; block = 256 (4 waves, 32 q-rows each).
// R8/R9 bracketed QBLK=64 out (spills at 128-VGPR cap; occupancy at 176 uncapped);
// this 124-VGPR point is the structure's optimum.
__global__ __launch_bounds__(256) void k_attn(const unsigned short* __restrict__ Qb,
                                              const unsigned short* __restrict__ Kb,
                                              const unsigned short* __restrict__ Vtb,
                                              unsigned short* __restrict__ Ob) {
    __shared__ short Ks[2][64 * 64];   // [kpos 64][hd 64], 16B chunks XOR-swizzled by row&7
    __shared__ short Vs[2][64 * 64];   // [hd 64][k 64], same swizzle

    const int tid = threadIdx.x;
    const int lane = tid & 63;
    const int wid = tid >> 6;
    // XCD-chunked swizzle (1024 wgs, 128/XCD): 8 whole heads per XCD -> K/V L2-resident
    const int lb = (blockIdx.x & 7) * 128 + (blockIdx.x >> 3);
    const int bh = lb >> 4;
    const int qt = lb & 15;
    const int c = lane & 31;
    const int hi = lane >> 5;

    const unsigned short* Qh = Qb + (size_t)bh * SEQ * 64;
    const unsigned short* Kh = Kb + (size_t)bh * SEQ * 64;
    const unsigned short* Vh = Vtb + (size_t)bh * 64 * SEQ;

    const int q0 = qt * 128 + wid * 32;

    // Q as B-operand: lane (c,hi) holds Q[q0+c][kc*16 + hi*8 + j]
    bf16x8 qf[4];
#pragma unroll
    for (int kc = 0; kc < 4; ++kc)
        qf[kc] = *(const bf16x8*)&Qh[(size_t)(q0 + c) * 64 + kc * 16 + hi * 8];

    f32x16 oacc[2];
    f32x16 lacc;
    f32x16 fz16;
#pragma unroll
    for (int r = 0; r < 16; ++r) { oacc[0][r] = 0.f; oacc[1][r] = 0.f; lacc[r] = 0.f; fz16[r] = 0.f; }

    auto stageK = [&](int buf, int kt) {
#pragma unroll
        for (int p = 0; p < 2; ++p) {
            int ci = wid * 128 + p * 64 + lane;
            int r_ = ci >> 3;
            int kc = (ci & 7) ^ (r_ & 7);
            gl_lds16(Kh + (size_t)(kt * 64 + r_) * 64 + kc * 8, &Ks[buf][ci * 8]);
        }
    };
    auto stageV = [&](int buf, int kt) {
#pragma unroll
        for (int p = 0; p < 2; ++p) {
            int ci = wid * 128 + p * 64 + lane;
            int r_ = ci >> 3;
            int kc = (ci & 7) ^ (r_ & 7);
            gl_lds16(Vh + (size_t)r_ * SEQ + kt * 64 + kc * 8, &Vs[buf][ci * 8]);
        }
    };

    stageK(0, 0);
    stageV(0, 0);
    __syncthreads();

    // cur passed as a literal so LDS addresses are loop-invariant (hoisted once)
    auto tile = [&](int cur, int kt) {
        if (kt + 1 < 32) { stageK(cur ^ 1, kt + 1); stageV(cur ^ 1, kt + 1); }

        // St = K Q^T  (swapped): D col=lane&31=q, row=kpos=(reg&3)+8*(reg>>2)+4*hi
        f32x16 st[2];
        __builtin_amdgcn_s_setprio(1);
#pragma unroll
        for (int t = 0; t < 2; ++t) {
            const int row = t * 32 + c;
            bf16x8 kf0 = *(const bf16x8*)&Ks[cur][row * 64 + (((hi) ^ (row & 7)) * 8)];
            st[t] = __builtin_amdgcn_mfma_f32_32x32x16_bf16(kf0, qf[0], fz16, 0, 0, 0);
#pragma unroll
            for (int kc = 1; kc < 4; ++kc) {
                bf16x8 kf = *(const bf16x8*)&Ks[cur][row * 64 + (((kc * 2 + hi) ^ (row & 7)) * 8)];
                st[t] = __builtin_amdgcn_mfma_f32_32x32x16_bf16(kf, qf[kc], st[t], 0, 0, 0);
            }
        }
        __builtin_amdgcn_s_setprio(0);

        // V fragments issued EARLY: their ds_read latency hides under softmax VALU
        bf16x8 vf[2][4];
#pragma unroll
        for (int nb = 0; nb < 2; ++nb) {
            const int row = nb * 32 + c;
#pragma unroll
            for (int ks = 0; ks < 4; ++ks)
                vf[nb][ks] = *(const bf16x8*)&Vs[cur][row * 64 + (((ks * 2 + hi) ^ (row & 7)) * 8)];
        }

        // P = exp2(S); accumulate row-sum partials per-reg (tree deferred to epilogue)
#pragma unroll
        for (int t = 0; t < 2; ++t)
#pragma unroll
            for (int r = 0; r < 16; ++r)
                st[t][r] = __builtin_amdgcn_exp2f(st[t][r]);
#pragma unroll
        for (int r = 0; r < 16; ++r)
            lacc[r] += st[0][r] + st[1][r];

        // P -> bf16 A-fragments via cvt_pk + permlane32_swap (T12, R5-verified)
        bf16x8 pa[4];
#pragma unroll
        for (int t = 0; t < 2; ++t) {
            unsigned int qd[8];
#pragma unroll
            for (int i = 0; i < 8; ++i) {
                float lo = st[t][2 * i], hg = st[t][2 * i + 1];
                unsigned int d;
                asm("v_cvt_pk_bf16_f32 %0, %1, %2" : "=v"(d) : "v"(lo), "v"(hg));
                qd[i] = d;
            }
            uint2v s02 = __builtin_amdgcn_permlane32_swap(qd[0], qd[2], false, false);
            uint2v s13 = __builtin_amdgcn_permlane32_swap(qd[1], qd[3], false, false);
            uint2v s46 = __builtin_amdgcn_permlane32_swap(qd[4], qd[6], false, false);
            uint2v s57 = __builtin_amdgcn_permlane32_swap(qd[5], qd[7], false, false);
            union { unsigned int u[4]; bf16x8 v; } pk0, pk1;
            pk0.u[0] = s02.x; pk0.u[1] = s13.x; pk0.u[2] = s02.y; pk0.u[3] = s13.y;
            pk1.u[0] = s46.x; pk1.u[1] = s57.x; pk1.u[2] = s46.y; pk1.u[3] = s57.y;
            pa[t * 2] = pk0.v;
            pa[t * 2 + 1] = pk1.v;
        }

        // O += P V : A=pa (row=q), B=V[k][hd]; D col=hd=nb*32+c, row=q over regs/hi
        __builtin_amdgcn_s_setprio(1);
#pragma unroll
        for (int ks = 0; ks < 4; ++ks) {
            oacc[0] = __builtin_amdgcn_mfma_f32_32x32x16_bf16(pa[ks], vf[0][ks], oacc[0], 0, 0, 0);
            oacc[1] = __builtin_amdgcn_mfma_f32_32x32x16_bf16(pa[ks], vf[1][ks], oacc[1], 0, 0, 0);
        }
        __builtin_amdgcn_s_setprio(0);

        __syncthreads();
    };

    for (int kt = 0; kt < 32; kt += 2) { tile(0, kt); tile(1, kt + 1); }

    // final row-sum: tree over the 16 partials, then hi-half exchange
    float lred[16];
#pragma unroll
    for (int r = 0; r < 16; ++r) lred[r] = lacc[r];
#pragma unroll
    for (int s2 = 8; s2 > 0; s2 >>= 1)
#pragma unroll
        for (int r = 0; r < s2; ++r) lred[r] += lred[r + s2];
    const float l_all = lred[0] + __shfl_xor(lred[0], 32);

    // epilogue: O[q][hd] with q=(r&3)+8*(r>>2)+4*hi, hd=nb*32+c; l gathered per row
    const int b_ = bh >> 4, h_ = bh & 15;
    const float linv = 1.0f / l_all;
#pragma unroll
    for (int r = 0; r < 16; ++r) {
        const int qrow = (r & 3) + 8 * (r >> 2) + 4 * hi;
        const float fr = __shfl(linv, qrow);
        const size_t mrow = (size_t)b_ * SEQ + q0 + qrow;
#pragma unroll
        for (int nb = 0; nb < 2; ++nb)
            Ob[mrow * DM + h_ * 64 + nb * 32 + c] = f2bf(oacc[nb][r] * fr);
    }
}

// ---------------- output GEMM: [8192,1024] x [1024,1024]^T + bias -> fp32 ----------------
// Same counted-vmcnt 2-phase loop as k_qkv.
__global__ __launch_bounds__(256) void k_out(const unsigned short* __restrict__ A,
                                             const unsigned short* __restrict__ W,
                                             const float* __restrict__ bias,
                                             float* __restrict__ O) {
    __shared__ short As[2][128 * 32];
    __shared__ short Bs[2][128 * 32];

    const int tid = threadIdx.x;
    const int lane = tid & 63;
    const int wid = tid >> 6;
    const int lr = lane & 15, g = lane >> 4;
    // XCD-chunked swizzle (512 wgs, 64/XCD)
    const int lb = (blockIdx.x & 7) * 64 + (blockIdx.x >> 3);
    const int bm = lb / (DM / 128);
    const int bn = lb % (DM / 128);
    const int m0 = bm * 128, n0 = bn * 128;
    const int wr = (wid >> 1) * 64, wc = (wid & 1) * 64;

    const f32x4 fz = {0.f, 0.f, 0.f, 0.f};
    f32x4 acc[4][4];
#pragma unroll
    for (int i = 0; i < 4; ++i)
#pragma unroll
        for (int j = 0; j < 4; ++j) acc[i][j] = fz;

    auto stage = [&](int buf, int kt) {
#pragma unroll
        for (int p = 0; p < 2; ++p) {
            int c = wid * 128 + p * 64 + lane;
            int r_ = c >> 2;
            int kc = (c & 3) ^ (r_ & 3);
            gl_lds16(A + (size_t)(m0 + r_) * DM + kt * 32 + kc * 8, &As[buf][c * 8]);
            gl_lds16(W + (size_t)(n0 + r_) * DM + kt * 32 + kc * 8, &Bs[buf][c * 8]);
        }
    };

    stage(0, 0);
    stage(1, 1);

    for (int kt = 0; kt < 32; ++kt) {
        const int cur = kt & 1;
        if (kt < 31) asm volatile("s_waitcnt vmcnt(4)" ::: "memory");
        else         asm volatile("s_waitcnt vmcnt(0)" ::: "memory");
        __builtin_amdgcn_s_barrier();

        bf16x8 a[4], b[4];
#pragma unroll
        for (int i = 0; i < 4; ++i) {
            int ra = wr + i * 16 + lr;
            a[i] = *(const bf16x8*)&As[cur][ra * 32 + ((g ^ (ra & 3)) * 8)];
            int rb = wc + i * 16 + lr;
            b[i] = *(const bf16x8*)&Bs[cur][rb * 32 + ((g ^ (rb & 3)) * 8)];
        }
        asm volatile("s_waitcnt lgkmcnt(0)" ::: "memory");
        __builtin_amdgcn_sched_barrier(0);
        __builtin_amdgcn_s_barrier();
        if (kt + 2 < 32) stage(cur, kt + 2);

#pragma unroll
        for (int i = 0; i < 4; ++i)
#pragma unroll
            for (int j = 0; j < 4; ++j)
                acc[i][j] = __builtin_amdgcn_mfma_f32_16x16x32_bf16(a[i], b[j], acc[i][j], 0, 0, 0);
    }

#pragma unroll
    for (int j = 0; j < 4; ++j) {
        const int col = n0 + wc + j * 16 + lr;
        const float bv = bias[col];
#pragma unroll
        for (int i = 0; i < 4; ++i) {
            const int mb = m0 + wr + i * 16 + g * 4;
#pragma unroll
            for (int r = 0; r < 4; ++r)
                O[(size_t)(mb + r) * DM + col] = acc[i][j][r] + bv;
        }
    }
}

extern "C" void kernel_launch(void* const* d_in, const int* in_sizes, int n_in,
                              void* d_out, int out_size, void* d_ws, size_t ws_size,
                              hipStream_t stream) {
    const float* x    = (const float*)d_in[0];
    const float* Wqkv = (const float*)d_in[1];
    const float* bqkv = (const float*)d_in[2];
    const float* Wout = (const float*)d_in[3];
    const float* bout = (const float*)d_in[4];
    float* out = (float*)d_out;

    char* ws = (char*)d_ws;                                     // needs 88 MB
    unsigned short* xb   = (unsigned short*)(ws);               // 16 MB  x bf16
    unsigned short* wqb  = (unsigned short*)(ws + (16u << 20)); // 6 MB W_qkv bf16
    unsigned short* wob  = (unsigned short*)(ws + (22u << 20)); // 2 MB W_out bf16
    unsigned short* Qb   = (unsigned short*)(ws + (24u << 20)); // 16 MB
    unsigned short* Kb   = (unsigned short*)(ws + (40u << 20)); // 16 MB
    unsigned short* Vtb  = (unsigned short*)(ws + (56u << 20)); // 16 MB
    unsigned short* valb = (unsigned short*)(ws + (72u << 20)); // 16 MB

    k_cvt_all<<<12288, 256, 0, stream>>>(x, Wqkv, Wout, xb, wqb, wob);
    k_qkv<<<64 * 24, 256, 0, stream>>>(xb, wqb, bqkv, Qb, Kb, Vtb);
    k_attn<<<64 * 16, 256, 0, stream>>>(Qb, Kb, Vtb, valb);
    k_out<<<64 * 8, 256, 0, stream>>>(valb, wob, bout, out);
}